// Round 1
// baseline (168.157 us; speedup 1.0000x reference)
//
#include <hip/hip_runtime.h>
#include <stdint.h>

#define H 2048
#define B 16
#define S 2048
#define SCH 32          // s-chunks for context partials
#define SPC (S / SCH)   // 64 s per chunk

typedef __attribute__((ext_vector_type(4))) float f32x4;
typedef __attribute__((ext_vector_type(8))) __bf16 bf16x8;
typedef __attribute__((ext_vector_type(4))) short s16x4;

// ---------- helpers ----------
__device__ inline unsigned short f2bf(float f) {
    uint32_t u = __builtin_bit_cast(uint32_t, f);
    uint32_t r = (u + 0x7FFFu + ((u >> 16) & 1u)) >> 16;
    return (unsigned short)r;
}

__device__ inline void global_load_lds16(const unsigned short* g, unsigned short* l) {
    __builtin_amdgcn_global_load_lds(
        (const __attribute__((address_space(1))) void*)g,
        (__attribute__((address_space(3))) void*)l, 16, 0, 0);
}

__device__ inline float fast_tanh(float x) {
    float e = __expf(2.0f * x);
    return 1.0f - 2.0f / (e + 1.0f);
}

// ---------- fp32 -> bf16 conversion ----------
__global__ __launch_bounds__(256) void f32_to_bf16_kernel(
    const float* __restrict__ src, unsigned short* __restrict__ dst, int n4)
{
    int i = blockIdx.x * blockDim.x + threadIdx.x;
    int stride = gridDim.x * blockDim.x;
    for (; i < n4; i += stride) {
        f32x4 v = ((const f32x4*)src)[i];
        s16x4 o;
        #pragma unroll
        for (int j = 0; j < 4; ++j) o[j] = (short)f2bf(v[j]);
        ((s16x4*)dst)[i] = o;
    }
}

// ---------- q_proj = q @ W1^T + b1 : (16, 2048) ----------
__global__ __launch_bounds__(256) void qproj_kernel(
    const float* __restrict__ query,   // (1,16,16,2048); use t = 15 slice
    const float* __restrict__ w1,      // (2048,2048) row-major
    const float* __restrict__ w1b,     // (2048)
    float* __restrict__ qproj)         // (16,2048)
{
    int wid = threadIdx.x >> 6;
    int lane = threadIdx.x & 63;
    int h = blockIdx.x * 4 + wid;
    float acc[B];
    #pragma unroll
    for (int b = 0; b < B; ++b) acc[b] = 0.f;
    const float* wrow = w1 + (int64_t)h * H;
    for (int kc = 0; kc < H; kc += 256) {
        f32x4 w4 = *(const f32x4*)(wrow + kc + lane * 4);
        #pragma unroll
        for (int b = 0; b < B; ++b) {
            const float* q = query + ((int64_t)(b * 16 + 15)) * H + kc + lane * 4;
            f32x4 q4 = *(const f32x4*)q;
            acc[b] += w4.x * q4.x + w4.y * q4.y + w4.z * q4.z + w4.w * q4.w;
        }
    }
    #pragma unroll
    for (int b = 0; b < B; ++b) {
        float v = acc[b];
        #pragma unroll
        for (int off = 32; off > 0; off >>= 1) v += __shfl_down(v, off, 64);
        if (lane == 0) qproj[b * H + h] = v + w1b[h];
    }
}

// ---------- v_proj = values[0] @ W2^T + b2 : bf16 MFMA GEMM, C = A(MxK) * B(NxK)^T ----------
#define BM 128
#define BN 128
#define BK 32

__global__ __launch_bounds__(256) void gemm_bt_kernel(
    const unsigned short* __restrict__ A,   // (2048,2048) bf16, values[0]
    const unsigned short* __restrict__ Bm,  // (2048,2048) bf16, W2_w
    const float* __restrict__ bias,         // (2048) W2_b
    float* __restrict__ C)                  // (2048,2048) f32 v_proj
{
    __shared__ unsigned short smA[BM * BK];  // 8 KB, linear for global_load_lds
    __shared__ unsigned short smB[BN * BK];  // 8 KB

    int t = threadIdx.x;
    int lane = t & 63;
    int wid = t >> 6;
    int wr = wid >> 1, wc = wid & 1;           // 2x2 wave grid, each wave 64x64
    int brow = blockIdx.y * BM;
    int bcol = blockIdx.x * BN;
    int l15 = lane & 15;
    int lk = (lane >> 4) * 8;                  // k-offset of this lane's fragment

    f32x4 acc[4][4] = {};

    const unsigned short* gA = A + (int64_t)(brow + (t >> 2)) * H + (t & 3) * 8;
    const unsigned short* gB = Bm + (int64_t)(bcol + (t >> 2)) * H + (t & 3) * 8;
    unsigned short* ldsA = smA + t * 8;        // byte offset t*16 (lane-linear)
    unsigned short* ldsB = smB + t * 8;

    for (int k0 = 0; k0 < H; k0 += BK) {
        __syncthreads();
        global_load_lds16(gA + k0, ldsA);
        global_load_lds16(gA + 64 * H + k0, ldsA + 64 * BK);
        global_load_lds16(gB + k0, ldsB);
        global_load_lds16(gB + 64 * H + k0, ldsB + 64 * BK);
        __syncthreads();

        bf16x8 a[4], b[4];
        #pragma unroll
        for (int m = 0; m < 4; ++m)
            a[m] = *(const bf16x8*)&smA[(wr * 64 + m * 16 + l15) * BK + lk];
        #pragma unroll
        for (int n = 0; n < 4; ++n)
            b[n] = *(const bf16x8*)&smB[(wc * 64 + n * 16 + l15) * BK + lk];
        #pragma unroll
        for (int m = 0; m < 4; ++m)
            #pragma unroll
            for (int n = 0; n < 4; ++n)
                acc[m][n] = __builtin_amdgcn_mfma_f32_16x16x32_bf16(a[m], b[n], acc[m][n], 0, 0, 0);
    }

    // epilogue: C/D layout col = lane&15, row = (lane>>4)*4 + q  [m89-verified]
    #pragma unroll
    for (int m = 0; m < 4; ++m) {
        #pragma unroll
        for (int n = 0; n < 4; ++n) {
            int col = bcol + wc * 64 + n * 16 + l15;
            float bs = bias[col];
            #pragma unroll
            for (int q = 0; q < 4; ++q) {
                int row = brow + wr * 64 + m * 16 + (lane >> 4) * 4 + q;
                C[(int64_t)row * H + col] = acc[m][n][q] + bs;
            }
        }
    }
}

// ---------- scores[b,s] = V_w . tanh(q_proj[b] + v_proj[s]) + V_b ----------
__global__ __launch_bounds__(256) void scores_kernel(
    const float* __restrict__ vproj,  // (S,H)
    const float* __restrict__ qproj,  // (B,H)
    const float* __restrict__ vw,     // (H)
    const float* __restrict__ vbias,  // scalar
    float* __restrict__ scores)       // (B,S)
{
    int wid = threadIdx.x >> 6, lane = threadIdx.x & 63;
    int s = blockIdx.x * 4 + wid;
    float acc[B];
    #pragma unroll
    for (int b = 0; b < B; ++b) acc[b] = 0.f;
    const float* vrow = vproj + (int64_t)s * H;
    for (int hc = 0; hc < H; hc += 256) {
        f32x4 vp = *(const f32x4*)(vrow + hc + lane * 4);
        f32x4 w4 = *(const f32x4*)(vw + hc + lane * 4);
        #pragma unroll
        for (int b = 0; b < B; ++b) {
            f32x4 q4 = *(const f32x4*)(qproj + b * H + hc + lane * 4);
            #pragma unroll
            for (int j = 0; j < 4; ++j) {
                float x = q4[j] + vp[j];
                acc[b] += w4[j] * fast_tanh(x);
            }
        }
    }
    float vb0 = vbias[0];
    #pragma unroll
    for (int b = 0; b < B; ++b) {
        float v = acc[b];
        #pragma unroll
        for (int off = 32; off > 0; off >>= 1) v += __shfl_down(v, off, 64);
        if (lane == 0) scores[b * S + s] = v + vb0;
    }
}

// ---------- softmax over s per batch ----------
__global__ __launch_bounds__(256) void softmax_kernel(
    const float* __restrict__ scores, // (B,S)
    float* __restrict__ alphas)       // (B,S)
{
    __shared__ float red[8];
    int b = blockIdx.x;
    int t = threadIdx.x;
    int wid = t >> 6, lane = t & 63;
    const float* srow = scores + b * S;
    float v[8];
    float m = -1e30f;
    #pragma unroll
    for (int i = 0; i < 8; ++i) { v[i] = srow[t + i * 256]; m = fmaxf(m, v[i]); }
    #pragma unroll
    for (int off = 32; off > 0; off >>= 1) m = fmaxf(m, __shfl_xor(m, off, 64));
    if (lane == 0) red[wid] = m;
    __syncthreads();
    m = fmaxf(fmaxf(red[0], red[1]), fmaxf(red[2], red[3]));
    float sum = 0.f;
    #pragma unroll
    for (int i = 0; i < 8; ++i) { v[i] = __expf(v[i] - m); sum += v[i]; }
    #pragma unroll
    for (int off = 32; off > 0; off >>= 1) sum += __shfl_xor(sum, off, 64);
    if (lane == 0) red[4 + wid] = sum;
    __syncthreads();
    sum = red[4] + red[5] + red[6] + red[7];
    float inv = 1.f / sum;
    #pragma unroll
    for (int i = 0; i < 8; ++i) alphas[b * S + t + i * 256] = v[i] * inv;
}

// ---------- context partials: partial[sc][b][h] = sum_{s in chunk} alpha[b,s]*values[b,s,h] ----------
__global__ __launch_bounds__(256) void context_partial_kernel(
    const float* __restrict__ values,  // (B,S,H)
    const float* __restrict__ alphas,  // (B,S)
    float* __restrict__ partial)       // (SCH,B,H)
{
    int ht = blockIdx.x;   // 0..1
    int sc = blockIdx.y;   // 0..SCH-1
    int b  = blockIdx.z;   // 0..15
    int h = ht * 1024 + threadIdx.x * 4;
    const float* vbase = values + (int64_t)b * S * H + (int64_t)sc * SPC * H + h;
    const float* abase = alphas + b * S + sc * SPC;
    f32x4 acc = {};
    #pragma unroll 4
    for (int s = 0; s < SPC; ++s) {
        float a = abase[s];
        f32x4 v4 = *(const f32x4*)(vbase + (int64_t)s * H);
        acc += a * v4;
    }
    *(f32x4*)(partial + ((int64_t)(sc * B + b)) * H + h) = acc;
}

__global__ __launch_bounds__(256) void context_reduce_kernel(
    const float* __restrict__ partial, float* __restrict__ out)
{
    int idx = blockIdx.x * 256 + threadIdx.x;   // 0..B*H-1
    int b = idx >> 11, h = idx & 2047;
    float s = 0.f;
    #pragma unroll
    for (int c = 0; c < SCH; ++c) s += partial[((int64_t)(c * B + b)) * H + h];
    out[idx] = s;
}

// ---------- launch ----------
extern "C" void kernel_launch(void* const* d_in, const int* in_sizes, int n_in,
                              void* d_out, int out_size, void* d_ws, size_t ws_size,
                              hipStream_t stream) {
    const float* query  = (const float*)d_in[0];
    const float* values = (const float*)d_in[1];
    // d_in[2] = mask: all-ones, unused by the reference scoring
    const float* w1w = (const float*)d_in[3];
    const float* w1b = (const float*)d_in[4];
    const float* w2w = (const float*)d_in[5];
    const float* w2b = (const float*)d_in[6];
    const float* vw  = (const float*)d_in[7];
    const float* vb  = (const float*)d_in[8];

    float* out = (float*)d_out;
    float* context = out;           // (B,1,H) = 32768 floats
    float* alphas  = out + B * H;   // (B,1,S) = 32768 floats

    float* ws = (float*)d_ws;
    float* qproj   = ws;                                    // 32768 f32
    float* scores  = ws + 32768;                            // 32768 f32
    float* vproj   = ws + 65536;                            // 4194304 f32
    float* partial = ws + 65536 + 4194304;                  // SCH*B*H = 1048576 f32
    unsigned short* Vb  = (unsigned short*)(ws + 65536 + 4194304 + 1048576);
    unsigned short* W2b = Vb + S * H;                       // 2 x 8.4 MB bf16

    f32_to_bf16_kernel<<<1024, 256, 0, stream>>>(values, Vb, (S * H) / 4);
    f32_to_bf16_kernel<<<1024, 256, 0, stream>>>(w2w, W2b, (H * H) / 4);
    qproj_kernel<<<H / 4, 256, 0, stream>>>(query, w1w, w1b, qproj);
    gemm_bt_kernel<<<dim3(H / BN, S / BM), 256, 0, stream>>>(Vb, W2b, w2b, vproj);
    scores_kernel<<<S / 4, 256, 0, stream>>>(vproj, qproj, vw, vb, scores);
    softmax_kernel<<<B, 256, 0, stream>>>(scores, alphas);
    context_partial_kernel<<<dim3(2, SCH, B), 256, 0, stream>>>(values, alphas, partial);
    context_reduce_kernel<<<(B * H) / 256, 256, 0, stream>>>(partial, context);
}